// Round 2
// baseline (124.790 us; speedup 1.0000x reference)
//
#include <hip/hip_runtime.h>
#include <stdint.h>
#include <stddef.h>

// Problem constants (fixed by the reference).
#define BSZ  256
#define NSZ  4096
#define CIN  8
#define KNB  9
#define DOUT 8
#define NSUB 2

typedef __fp16   fh2  __attribute__((ext_vector_type(2)));   // builtin-compatible half2
typedef float    f4   __attribute__((ext_vector_type(4)));
typedef uint32_t u32x4 __attribute__((ext_vector_type(4)));

static __device__ __forceinline__ uint32_t pk_f16(float a, float b) {
    fh2 h = __builtin_amdgcn_cvt_pkrtz(a, b);   // v_cvt_pkrtz_f16_f32
    return __builtin_bit_cast(uint32_t, h);
}

static __device__ __forceinline__ float dot2(uint32_t a, uint32_t b, float c) {
#if __has_builtin(__builtin_amdgcn_fdot2)
    return __builtin_amdgcn_fdot2(__builtin_bit_cast(fh2, a),
                                  __builtin_bit_cast(fh2, b), c, false);
#else
    fh2 x = __builtin_bit_cast(fh2, a), y = __builtin_bit_cast(fh2, b);
    return c + (float)x[0] * (float)y[0] + (float)x[1] * (float)y[1];
#endif
}

// Pack weight (S,CIN,KNB,DOUT) fp32 -> wp[s][k][cp][d] : u32 = (f16 w[2cp], f16 w[2cp+1])
__global__ void pack_w_kernel(const float* __restrict__ w, uint32_t* __restrict__ wp) {
    int i = threadIdx.x;
    if (i >= NSUB * KNB * 4 * DOUT) return;
    int d = i & 7, cp = (i >> 3) & 3, r = i >> 5;
    int k = r % KNB, s = r / KNB;
    float w0 = w[((s * CIN + 2 * cp    ) * KNB + k) * DOUT + d];
    float w1 = w[((s * CIN + 2 * cp + 1) * KNB + k) * DOUT + d];
    wp[i] = pk_f16(w0, w1);
}

__global__ __launch_bounds__(512) void latconv_kernel(
    const float* __restrict__ x, const int* __restrict__ nbh,
    const int* __restrict__ sub, const uint32_t* __restrict__ wp,
    const float* __restrict__ bias, float* __restrict__ out)
{
    // xl[j][cp] : 8 channels of column j as 4 packed fp16 pairs (16B row) = 64 KiB
    __shared__ __align__(16) uint32_t xl[NSZ * 4];

    const int b = blockIdx.x;
    const int t = threadIdx.x;
    const float* xb = x + (size_t)b * (CIN * NSZ);

    // ---- stage x[b] -> LDS (fp32 -> packed fp16, transpose to [j][c]) ----
    #pragma unroll
    for (int g = 0; g < 2; ++g) {
        const int j0 = 4 * t + 2048 * g;          // this thread owns columns j0..j0+3
        f4 v[CIN];
        #pragma unroll
        for (int c = 0; c < CIN; ++c)
            v[c] = *reinterpret_cast<const f4*>(xb + c * NSZ + j0);   // coalesced 16B
        #pragma unroll
        for (int jj = 0; jj < 4; ++jj) {
            u32x4 row;
            #pragma unroll
            for (int cp = 0; cp < 4; ++cp)
                row[cp] = pk_f16(v[2 * cp][jj], v[2 * cp + 1][jj]);
            *reinterpret_cast<u32x4*>(&xl[(size_t)(j0 + jj) * 4]) = row;  // ds_write_b128
        }
    }

    // bias rows for both sites (uniform scalar loads)
    float bias0[DOUT], bias1[DOUT];
    #pragma unroll
    for (int d = 0; d < DOUT; ++d) { bias0[d] = bias[d]; bias1[d] = bias[DOUT + d]; }

    __syncthreads();

    // ---- compute: each thread owns 2 groups of 4 consecutive n ----
    #pragma unroll
    for (int grp = 0; grp < 2; ++grp) {
        const int n0 = 4 * t + 2048 * grp;

        const int4 s4 = *reinterpret_cast<const int4*>(sub + n0);
        int sv[4] = { s4.x, s4.y, s4.z, s4.w };

        float acc[4][DOUT];
        #pragma unroll
        for (int i = 0; i < 4; ++i) {
            #pragma unroll
            for (int d = 0; d < DOUT; ++d)
                acc[i][d] = sv[i] ? bias1[d] : bias0[d];
        }

        for (int k = 0; k < KNB; ++k) {
            // gather 4 neighbor columns from LDS (one b128 each: all 8 channels)
            u32x4 xv[4];
            #pragma unroll
            for (int i = 0; i < 4; ++i) {
                const int j = nbh[(n0 + i) * KNB + k];
                xv[i] = *reinterpret_cast<const u32x4*>(&xl[(size_t)j * 4]);
            }
            #pragma unroll
            for (int cp = 0; cp < 4; ++cp) {
                const uint32_t* w0p = wp + ((0 * KNB + k) * 4 + cp) * 8;
                const uint32_t* w1p = wp + ((1 * KNB + k) * 4 + cp) * 8;
                uint32_t wq0[DOUT], wq1[DOUT];
                #pragma unroll
                for (int d = 0; d < DOUT; ++d) { wq0[d] = w0p[d]; wq1[d] = w1p[d]; }
                #pragma unroll
                for (int i = 0; i < 4; ++i) {
                    #pragma unroll
                    for (int d = 0; d < DOUT; ++d) {
                        const uint32_t wsel = sv[i] ? wq1[d] : wq0[d];   // v_cndmask
                        acc[i][d] = dot2(xv[i][cp], wsel, acc[i][d]);    // v_dot2_f32_f16
                    }
                }
            }
        }

        // coalesced stores: per d, 4 consecutive n per lane -> contiguous 1KB per wave
        #pragma unroll
        for (int d = 0; d < DOUT; ++d) {
            f4 o = { acc[0][d], acc[1][d], acc[2][d], acc[3][d] };
            *reinterpret_cast<f4*>(out + ((size_t)b * DOUT + d) * NSZ + n0) = o;
        }
    }
}

extern "C" void kernel_launch(void* const* d_in, const int* in_sizes, int n_in,
                              void* d_out, int out_size, void* d_ws, size_t ws_size,
                              hipStream_t stream) {
    const float* x    = (const float*)d_in[0];
    const int*   nbh  = (const int*)d_in[1];
    const int*   sub  = (const int*)d_in[2];
    const float* w    = (const float*)d_in[3];
    const float* bias = (const float*)d_in[4];
    float* out = (float*)d_out;
    uint32_t* wp = (uint32_t*)d_ws;   // 2304 B packed-weight table

    pack_w_kernel<<<1, 576, 0, stream>>>(w, wp);
    latconv_kernel<<<BSZ, 512, 0, stream>>>(x, nbh, sub, wp, bias, out);
}